// Round 1
// 324.990 us; speedup vs baseline: 1.0149x; 1.0149x over previous
//
#include <hip/hip_runtime.h>

// MultiHeadSelfAttention: B=4, C=256, S=4096, heads=8, d=32.
// 3-kernel pipeline, all GEMMs on mfma_f32_16x16x32_bf16, fp32 accumulate.
//   k_qkv : qkv = x @ Wqkv^T + b  -> Qr (b,h,S,d) pre-scaled by scale*log2e,
//                                     K  (b,h,S,d), Vt (b,h,d,S)   [bf16]
//   k_attn: flash attention, fixed-max softmax, key-split 2x per block.
//           P path is fully in-register: QK output -> exp2 -> v_cvt_pk_bf16_f32
//           -> permlane32_swap+permlane16_swap relayout into the PV A-fragment
//           (no LDS round-trip, no bank conflicts). Row sums via ones-MFMA so
//           numerator/denominator use identical rounded bf16 P.
//   k_proj: out = O @ Wproj^T + b -> (B,C,S) fp32 via per-wave LDS transpose

typedef __attribute__((ext_vector_type(8))) short short8;  // 8 x bf16 MFMA frag
typedef __attribute__((ext_vector_type(4))) float f4;

__device__ __forceinline__ short f2bs(float f) {  // fp32 -> bf16 (RNE)
  union { float f; unsigned u; } v; v.f = f;
  unsigned r = v.u + 0x7FFFu + ((v.u >> 16) & 1u);
  return (short)(r >> 16);
}

__device__ __forceinline__ short8 cvt8(f4 a, f4 b) {
  short8 o;
  o[0] = f2bs(a[0]); o[1] = f2bs(a[1]); o[2] = f2bs(a[2]); o[3] = f2bs(a[3]);
  o[4] = f2bs(b[0]); o[5] = f2bs(b[1]); o[6] = f2bs(b[2]); o[7] = f2bs(b[3]);
  return o;
}

// ---------------------------------------------------------------- kernel 1
__global__ __launch_bounds__(256) void k_qkv(
    const float* __restrict__ x, const float* __restrict__ w,
    const float* __restrict__ bias,
    short* __restrict__ Qr, short* __restrict__ Kq, short* __restrict__ Vt) {
  const int tid = threadIdx.x;
  const int L = tid & 63, wv = tid >> 6;
  const int ln15 = L & 15, quad = L >> 4;
  const int mt = blockIdx.x;
  const int b = mt >> 6;
  const int s0 = (mt & 63) << 6;
  const int j0 = blockIdx.y << 6;
  const int jw = j0 + wv * 16;

  __shared__ __align__(16) short tl[4 * 64 * 16];  // per-wave transpose buffer

  f4 acc[4] = {{0,0,0,0},{0,0,0,0},{0,0,0,0},{0,0,0,0}};
  const float* wb = w + (jw + ln15) * 256 + quad * 8;
  const float* xb = x + b * (256 * 4096) + s0 + ln15;

#pragma unroll 2
  for (int cb = 0; cb < 256; cb += 32) {
    f4 a0 = *(const f4*)(wb + cb);
    f4 a1 = *(const f4*)(wb + cb + 4);
    short8 af = cvt8(a0, a1);
    const float* xc = xb + (cb + quad * 8) * 4096;
#pragma unroll
    for (int sub = 0; sub < 4; ++sub) {
      const float* xs = xc + sub * 16;
      short8 bf;
#pragma unroll
      for (int jj = 0; jj < 8; ++jj) bf[jj] = f2bs(xs[jj * 4096]);
      acc[sub] = __builtin_amdgcn_mfma_f32_16x16x32_bf16(af, bf, acc[sub], 0, 0, 0);
    }
  }

  float bj[4];
#pragma unroll
  for (int r = 0; r < 4; ++r) bj[r] = bias[jw + quad * 4 + r];

  const int type = j0 >> 8;  // 0=Q 1=K 2=V
  if (type == 2) {
    const int jv = jw - 512;
    const int h = jv >> 5;
    const int dbase = jv & 31;
#pragma unroll
    for (int r = 0; r < 4; ++r) {
      const int d = dbase + quad * 4 + r;
      short* vp = Vt + (size_t)((b * 8 + h) * 32 + d) * 4096 + s0 + ln15;
#pragma unroll
      for (int sub = 0; sub < 4; ++sub)
        vp[sub * 16] = f2bs(acc[sub][r] + bj[r]);
    }
  } else {
    const float qsc = 0.17677669529663689f * 1.44269504088896f;
    const float mul = (type == 0) ? qsc : 1.0f;
    short* dst = (type == 0) ? Qr : Kq;
    const int hj = jw & 255;
    short* tw = tl + wv * 1024;
#pragma unroll
    for (int sub = 0; sub < 4; ++sub) {
      const int s = sub * 16 + ln15;
      const int swz = (s >> 2) & 1;
#pragma unroll
      for (int r = 0; r < 4; ++r) {
        const int dl = quad * 4 + r;
        tw[s * 16 + (((dl >> 3) ^ swz) * 8) + (dl & 7)] = f2bs((acc[sub][r] + bj[r]) * mul);
      }
    }
    const int h = hj >> 5;
    const int d0 = hj & 31;
#pragma unroll
    for (int i = 0; i < 2; ++i) {
      const int sl = i * 32 + (L >> 1);
      const int gg = L & 1;
      const int g2 = gg ^ ((sl >> 2) & 1);
      short8 row = *(const short8*)(tw + sl * 16 + g2 * 8);
      *(short8*)(dst + (size_t)((b * 8 + h) * 4096 + s0 + sl) * 32 + d0 + gg * 8) = row;
    }
  }
}

// ---------------------------------------------------------------- kernel 2
// Block = 4 waves: wave wv -> q-tile (wv&1), key-half (wv>>1).
// Each wave: 32 q x 2048 keys, chunks of 64 keys. Per chunk, per q-tile (qs):
//   QK: A=K (m=key), B=Q (n=q) -> lane holds q=ln15, keys quad*4+r
//   exp2 -> v_cvt_pk_bf16_f32 (keys 16t+4*quad+{2u,2u+1} per dword)
//   relayout: for (f,u): permlane32_swap(dw[2f][u], dw[2f+1][u]) then
//             permlane16_swap -> yields PV A-frag dwords j=u and j=u+2
//             (frag f covers chunk keys 32f..32f+31; lane keys 8*quad+0..7)
//   l: accl = mfma(P_frag, ones) -> row sums of the ROUNDED P on the MFMA pipe
//   PV: acc[qs][dg] += mfma(P_frag_f, Vt_frag[f][dg])
// Epilogue: upper waves dump acc(fp32)+accl into LDS; barrier; lower waves
// combine, normalize (l consistent with numerator), store O (b,S,C) bf16.
__global__ __launch_bounds__(256, 5) void k_attn(
    const short* __restrict__ Qr, const short* __restrict__ Kq,
    const short* __restrict__ Vt, short* __restrict__ O) {
  const int tid = threadIdx.x;
  const int L = tid & 63, wv = tid >> 6;
  const int ln15 = L & 15, quad = L >> 4;
  const int bh = blockIdx.y;
  const int b = bh >> 3, h = bh & 7;
  const int qt = wv & 1, half = wv >> 1;
  const int qb = blockIdx.x * 64 + qt * 32;

  const short* Qb = Qr + (size_t)bh * 4096 * 32;
  const short* Kb = Kq + (size_t)bh * 4096 * 32 + half * 2048 * 32;
  const short* Vb = Vt + (size_t)bh * 32 * 4096 + half * 2048;

  __shared__ float cbuf[2][32 * 33];  // upper-wave acc dump, padded stride
  __shared__ float l_up[2][32];

  // Q B-frags (n=q): direct 16B loads, once per wave
  short8 qf[2];
#pragma unroll
  for (int qs = 0; qs < 2; ++qs)
    qf[qs] = *(const short8*)(Qb + (qb + qs * 16 + ln15) * 32 + quad * 8);

  short8 ones;
#pragma unroll
  for (int j = 0; j < 8; ++j) ones[j] = (short)0x3F80;  // bf16 1.0

  f4 acc[2][2] = {{{0,0,0,0},{0,0,0,0}},{{0,0,0,0},{0,0,0,0}}};
  f4 accl[2] = {{0,0,0,0},{0,0,0,0}};
  const f4 z4 = {0.f, 0.f, 0.f, 0.f};

  const short* kp = Kb + ln15 * 32 + quad * 8;
  const short* vp = Vb + ln15 * 4096 + quad * 8;

  for (int kb = 0; kb < 2048; kb += 64) {
    short8 vf[2][2];  // [f = key 32-group][dg = d-half]
#pragma unroll
    for (int f = 0; f < 2; ++f)
#pragma unroll
      for (int dg = 0; dg < 2; ++dg)
        vf[f][dg] = *(const short8*)(vp + dg * (16 * 4096) + kb + f * 32);

#pragma unroll
    for (int qs = 0; qs < 2; ++qs) {
      // ---- S = K Q^T, exp2, pack: dwa[t][u] = bf16 pair, keys 16t+4q+{2u,2u+1}
      int dwa[4][2];
#pragma unroll
      for (int t = 0; t < 4; ++t) {
        short8 kf = *(const short8*)(kp + (kb + t * 16) * 32);
        f4 sc = __builtin_amdgcn_mfma_f32_16x16x32_bf16(kf, qf[qs], z4, 0, 0, 0);
        float p0 = __builtin_amdgcn_exp2f(sc[0]);
        float p1 = __builtin_amdgcn_exp2f(sc[1]);
        float p2 = __builtin_amdgcn_exp2f(sc[2]);
        float p3 = __builtin_amdgcn_exp2f(sc[3]);
        asm("v_cvt_pk_bf16_f32 %0, %1, %2" : "=v"(dwa[t][0]) : "v"(p0), "v"(p1));
        asm("v_cvt_pk_bf16_f32 %0, %1, %2" : "=v"(dwa[t][1]) : "v"(p2), "v"(p3));
      }
      // ---- in-register relayout to PV A-frags (verified lane mapping):
      // dest quad Qn, frag f, dword j needs pair 16f+4Qn+j which lives at
      // register dwa[2f+(Qn>>1)][j&1], source quad (2Qn+(j>>1))&3.
      union { int i[4]; short8 s; } pk[2];
#pragma unroll
      for (int f = 0; f < 2; ++f)
#pragma unroll
        for (int u = 0; u < 2; ++u) {
          int a = dwa[2 * f][u];
          int c = dwa[2 * f + 1][u];
          asm("v_permlane32_swap_b32 %0, %1" : "+v"(a), "+v"(c));
          asm("v_permlane16_swap_b32 %0, %1" : "+v"(a), "+v"(c));
          pk[f].i[u] = a;       // dword j = u
          pk[f].i[u + 2] = c;   // dword j = u + 2
        }
      // ---- l: row-sum of rounded P via ones-MFMA (MFMA pipe, not VALU)
      accl[qs] = __builtin_amdgcn_mfma_f32_16x16x32_bf16(pk[0].s, ones, accl[qs], 0, 0, 0);
      accl[qs] = __builtin_amdgcn_mfma_f32_16x16x32_bf16(pk[1].s, ones, accl[qs], 0, 0, 0);
      // ---- O += P V
      acc[qs][0] = __builtin_amdgcn_mfma_f32_16x16x32_bf16(pk[0].s, vf[0][0], acc[qs][0], 0, 0, 0);
      acc[qs][1] = __builtin_amdgcn_mfma_f32_16x16x32_bf16(pk[0].s, vf[0][1], acc[qs][1], 0, 0, 0);
      acc[qs][0] = __builtin_amdgcn_mfma_f32_16x16x32_bf16(pk[1].s, vf[1][0], acc[qs][0], 0, 0, 0);
      acc[qs][1] = __builtin_amdgcn_mfma_f32_16x16x32_bf16(pk[1].s, vf[1][1], acc[qs][1], 0, 0, 0);
    }
  }

  // ---- combine key halves through LDS.
  // accl[qs][r] = l-sum for q-row quad*4+r (identical across ln15 by C/D layout)
  if (half == 1) {
    float* cw = cbuf[qt];
#pragma unroll
    for (int qs = 0; qs < 2; ++qs) {
#pragma unroll
      for (int dg = 0; dg < 2; ++dg)
#pragma unroll
        for (int r = 0; r < 4; ++r)
          cw[(qs * 16 + quad * 4 + r) * 33 + dg * 16 + ln15] = acc[qs][dg][r];
      if (ln15 == 0) {
#pragma unroll
        for (int r = 0; r < 4; ++r)
          l_up[qt][qs * 16 + quad * 4 + r] = accl[qs][r];
      }
    }
  }
  __syncthreads();
  if (half == 0) {
    const float* cu = cbuf[qt];
#pragma unroll
    for (int qs = 0; qs < 2; ++qs) {
#pragma unroll
      for (int r = 0; r < 4; ++r) {
        const float lup = l_up[qt][qs * 16 + quad * 4 + r];
        const float rl = 1.0f / (accl[qs][r] + lup);
        const int sg = qb + qs * 16 + quad * 4 + r;
        short* op = O + (size_t)(b * 4096 + sg) * 256 + h * 32 + ln15;
        const int ci = (qs * 16 + quad * 4 + r) * 33 + ln15;
        op[0]  = f2bs((acc[qs][0][r] + cu[ci]) * rl);
        op[16] = f2bs((acc[qs][1][r] + cu[ci + 16]) * rl);
      }
    }
  }
}

// ---------------------------------------------------------------- kernel 3
__global__ __launch_bounds__(256) void k_proj(
    const short* __restrict__ O, const float* __restrict__ w,
    const float* __restrict__ bias, float* __restrict__ out) {
  const int tid = threadIdx.x;
  const int L = tid & 63, wv = tid >> 6;
  const int ln15 = L & 15, quad = L >> 4;
  const int m0 = blockIdx.x * 64 + wv * 16;
  const int n0 = blockIdx.y << 6;
  const int b = m0 >> 12, s0 = m0 & 4095;

  f4 acc[4] = {{0,0,0,0},{0,0,0,0},{0,0,0,0},{0,0,0,0}};
  const short* Ob = O + (size_t)(m0 + ln15) * 256 + quad * 8;
  const float* wb = w + (n0 + ln15) * 256 + quad * 8;

#pragma unroll 2
  for (int cb = 0; cb < 256; cb += 32) {
    short8 af = *(const short8*)(Ob + cb);
#pragma unroll
    for (int sub = 0; sub < 4; ++sub) {
      f4 b0 = *(const f4*)(wb + sub * (16 * 256) + cb);
      f4 b1 = *(const f4*)(wb + sub * (16 * 256) + cb + 4);
      short8 bf = cvt8(b0, b1);
      acc[sub] = __builtin_amdgcn_mfma_f32_16x16x32_bf16(af, bf, acc[sub], 0, 0, 0);
    }
  }

  __shared__ float tl[4][64 * 17];  // per-wave 64c x 16m fp32, stride 17
  float* tw = tl[wv];
#pragma unroll
  for (int sub = 0; sub < 4; ++sub) {
    const float bv = bias[n0 + sub * 16 + ln15];
#pragma unroll
    for (int r = 0; r < 4; ++r)
      tw[(sub * 16 + ln15) * 17 + quad * 4 + r] = acc[sub][r] + bv;
  }
#pragma unroll
  for (int i = 0; i < 4; ++i) {
    const int c = i * 16 + (L >> 2);
    const int ms = (L & 3) * 4;
    f4 v;
#pragma unroll
    for (int j = 0; j < 4; ++j) v[j] = tw[c * 17 + ms + j];
    *(f4*)(out + (size_t)b * (256 * 4096) + (size_t)(n0 + c) * 4096 + s0 + ms) = v;
  }
}

// ---------------------------------------------------------------- launcher
extern "C" void kernel_launch(void* const* d_in, const int* in_sizes, int n_in,
                              void* d_out, int out_size, void* d_ws, size_t ws_size,
                              hipStream_t stream) {
  const float* x      = (const float*)d_in[0];
  const float* w_qkv  = (const float*)d_in[1];
  const float* b_qkv  = (const float*)d_in[2];
  const float* w_proj = (const float*)d_in[3];
  const float* b_proj = (const float*)d_in[4];
  float* out = (float*)d_out;

  const size_t SEG = (size_t)4 * 8 * 4096 * 32;  // 4.19M bf16 elems = 8 MiB
  short* Qr = (short*)d_ws;
  short* Kq = Qr + SEG;
  short* Vt = Kq + SEG;
  short* O  = Vt + SEG;  // (B,S,C) bf16

  k_qkv <<<dim3(256, 12), 256, 0, stream>>>(x, w_qkv, b_qkv, Qr, Kq, Vt);
  k_attn<<<dim3(64, 32),  256, 0, stream>>>(Qr, Kq, Vt, O);
  k_proj<<<dim3(256, 4),  256, 0, stream>>>(O, w_proj, b_proj, out);
}